// Round 1
// baseline (650.023 us; speedup 1.0000x reference)
//
#include <hip/hip_runtime.h>
#include <hip/hip_bf16.h>

// Problem constants
#define H_ 8
#define D_ 512
#define DK_ 64
#define B_ 16
#define N_ 8192
#define M_ (B_ * N_)  // 131072 rows

typedef __attribute__((ext_vector_type(8))) short short8;
typedef __attribute__((ext_vector_type(4))) float floatx4;

// ---------------------------------------------------------------- helpers
__device__ __forceinline__ void glds16(const void* g, void* l) {
    // 16B-wide direct global->LDS DMA. LDS dest = wave-uniform base + lane*16.
    __builtin_amdgcn_global_load_lds((const __attribute__((address_space(1))) void*)g,
                                     (__attribute__((address_space(3))) void*)l,
                                     16, 0, 0);
}

__device__ __forceinline__ unsigned short f2bf(float f) {
    unsigned u = __float_as_uint(f);
    return (unsigned short)((u + 0x7fffu + ((u >> 16) & 1u)) >> 16);  // RNE
}

// ---------------------------------------------------------------- kernel 0: fp32 -> bf16
__global__ __launch_bounds__(256) void cvt_kernel(const float* __restrict__ src,
                                                  unsigned short* __restrict__ dst, int n4) {
    int i = blockIdx.x * blockDim.x + threadIdx.x;
    int stride = gridDim.x * blockDim.x;
    for (; i < n4; i += stride) {
        float4 v = ((const float4*)src)[i];
        ushort4 o;
        o.x = f2bf(v.x); o.y = f2bf(v.y); o.z = f2bf(v.z); o.w = f2bf(v.w);
        ((ushort4*)dst)[i] = o;
    }
}

// ---------------------------------------------------------------- kernel 1: fused double-GEMM + gate + query-dot
// C_k[m,j] = sum_d x[m,d]*Wk[j,d]; C_g likewise. Then
// s[b,h,n] = sum_{dk} q[h,dk] * tanh(C_k)*sigmoid(C_g), head h fixed per 64-col span.
// Tile: BM=128 x BN=128 (2 heads), BK=32, 256 threads, wave -> 64x64 quadrant (4x4 MFMA 16x16x32).
__global__ __launch_bounds__(256, 2) void gemm_score_kernel(
    const unsigned short* __restrict__ xb,   // (M_, 512) bf16
    const unsigned short* __restrict__ wkb,  // (512, 512) bf16
    const unsigned short* __restrict__ wgb,  // (512, 512) bf16
    const float* __restrict__ query,         // (8, 64) fp32
    float* __restrict__ s_buf)               // (B_, H_, N_) fp32
{
    __shared__ unsigned short lds_a[128 * 32];  // 8 KB
    __shared__ unsigned short lds_k[128 * 32];
    __shared__ unsigned short lds_g[128 * 32];

    const int t = threadIdx.x;
    const int lane = t & 63;
    const int wave = t >> 6;
    const int wm = wave >> 1, wn = wave & 1;
    const int jc = blockIdx.x * 128;   // output-column tile (4 tiles)
    const int m0 = blockIdx.y * 128;   // row tile (1024 tiles)

    floatx4 acc_k[4][4], acc_g[4][4];
#pragma unroll
    for (int i = 0; i < 4; ++i)
#pragma unroll
        for (int j = 0; j < 4; ++j) { acc_k[i][j] = (floatx4)0.f; acc_g[i][j] = (floatx4)0.f; }

    // staging: tile = 128 rows x 4 chunks(16B) = 512 chunks; thread t does chunks t and 256+t
    const int r0 = t >> 2, c0 = t & 3;
    const int r1 = 64 + r0;
    const size_t xo0 = (size_t)(m0 + r0) * 512 + c0 * 8;
    const size_t xo1 = (size_t)(m0 + r1) * 512 + c0 * 8;
    const size_t wo0 = (size_t)(jc + r0) * 512 + c0 * 8;
    const size_t wo1 = (size_t)(jc + r1) * 512 + c0 * 8;
    unsigned short* la0 = lds_a + t * 8;
    unsigned short* la1 = lds_a + (256 + t) * 8;
    unsigned short* lk0 = lds_k + t * 8;
    unsigned short* lk1 = lds_k + (256 + t) * 8;
    unsigned short* lg0 = lds_g + t * 8;
    unsigned short* lg1 = lds_g + (256 + t) * 8;

    const int fr = lane & 15;         // fragment row (A) / col (B)
    const int fk = (lane >> 4) * 8;   // fragment k offset

    for (int k0 = 0; k0 < 512; k0 += 32) {
        glds16(xb + xo0 + k0, la0);
        glds16(xb + xo1 + k0, la1);
        glds16(wkb + wo0 + k0, lk0);
        glds16(wkb + wo1 + k0, lk1);
        glds16(wgb + wo0 + k0, lg0);
        glds16(wgb + wo1 + k0, lg1);
        __syncthreads();

        short8 a[4], bk[4], bg[4];
#pragma unroll
        for (int mi = 0; mi < 4; ++mi)
            a[mi] = *(const short8*)(lds_a + (wm * 64 + mi * 16 + fr) * 32 + fk);
#pragma unroll
        for (int ni = 0; ni < 4; ++ni) {
            bk[ni] = *(const short8*)(lds_k + (wn * 64 + ni * 16 + fr) * 32 + fk);
            bg[ni] = *(const short8*)(lds_g + (wn * 64 + ni * 16 + fr) * 32 + fk);
        }
#pragma unroll
        for (int mi = 0; mi < 4; ++mi)
#pragma unroll
            for (int ni = 0; ni < 4; ++ni) {
                acc_k[mi][ni] = __builtin_amdgcn_mfma_f32_16x16x32_bf16(a[mi], bk[ni], acc_k[mi][ni], 0, 0, 0);
                acc_g[mi][ni] = __builtin_amdgcn_mfma_f32_16x16x32_bf16(a[mi], bg[ni], acc_g[mi][ni], 0, 0, 0);
            }
        __syncthreads();
    }

    // Epilogue: gated = tanh(K)*sigmoid(G); score contribution = q . gated, reduce over 16 lanes.
    // C/D layout (verified m89): col = lane&15, row = (lane>>4)*4 + reg.
    const int h = blockIdx.x * 2 + wn;  // this wave's head
    float qv[4];
#pragma unroll
    for (int ni = 0; ni < 4; ++ni) qv[ni] = query[h * 64 + ni * 16 + fr];

#pragma unroll
    for (int mi = 0; mi < 4; ++mi) {
#pragma unroll
        for (int r = 0; r < 4; ++r) {
            float v = 0.f;
#pragma unroll
            for (int ni = 0; ni < 4; ++ni) {
                float kv = acc_k[mi][ni][r];
                float gv = acc_g[mi][ni][r];
                float e2k = __expf(2.f * kv);
                float th = 1.f - 2.f / (e2k + 1.f);       // tanh, overflow-safe
                float sg = 1.f / (1.f + __expf(-gv));     // sigmoid
                v += qv[ni] * th * sg;
            }
            v += __shfl_xor(v, 1);
            v += __shfl_xor(v, 2);
            v += __shfl_xor(v, 4);
            v += __shfl_xor(v, 8);
            if (fr == 0) {
                int mg = m0 + wm * 64 + mi * 16 + (lane >> 4) * 4 + r;
                int b = mg >> 13, n = mg & 8191;
                s_buf[((size_t)(b * 8 + h) << 13) + n] = v;
            }
        }
    }
}

// ---------------------------------------------------------------- kernel 2: per-(b,h) softmax stats
__global__ __launch_bounds__(256) void stats_kernel(const float* __restrict__ s_buf,
                                                    float* __restrict__ mb, float* __restrict__ lb) {
    const int bh = blockIdx.x;  // 0..127
    const float* s = s_buf + ((size_t)bh << 13);
    const int t = threadIdx.x;
    float mx = -3.0e38f;
    for (int i = t; i < 8192; i += 256) mx = fmaxf(mx, s[i]);
#pragma unroll
    for (int m = 32; m > 0; m >>= 1) mx = fmaxf(mx, __shfl_xor(mx, m));
    __shared__ float red[8];
    if ((t & 63) == 0) red[t >> 6] = mx;
    __syncthreads();
    mx = fmaxf(fmaxf(red[0], red[1]), fmaxf(red[2], red[3]));
    float sum = 0.f;
    for (int i = t; i < 8192; i += 256) sum += __expf(s[i] - mx);
#pragma unroll
    for (int m = 32; m > 0; m >>= 1) sum += __shfl_xor(sum, m);
    if ((t & 63) == 0) red[4 + (t >> 6)] = sum;
    __syncthreads();
    if (t == 0) { mb[bh] = mx; lb[bh] = red[4] + red[5] + red[6] + red[7]; }
}

// ---------------------------------------------------------------- kernel 3: out[b,d] = sum_n w[b,h(d),n] * x[b,n,d]
__global__ __launch_bounds__(256) void out_kernel(
    const unsigned short* __restrict__ xb, const float* __restrict__ s_buf,
    const float* __restrict__ mb, const float* __restrict__ lb,
    float* __restrict__ out) {
    const int b = blockIdx.x >> 5;      // 16
    const int chunk = blockIdx.x & 31;  // 32 chunks of 256 rows
    const int n0 = chunk * 256;
    const int t = threadIdx.x;
    __shared__ float w[8 * 256];
    for (int i = t; i < 2048; i += 256) {
        int hh = i >> 8, nn = i & 255;
        int bh = b * 8 + hh;
        w[i] = __expf(s_buf[((size_t)bh << 13) + n0 + nn] - mb[bh]) / lb[bh];
    }
    __syncthreads();
    const int rg = t >> 6;            // 4 row-groups
    const int d0 = (t & 63) * 8;      // 8 bf16 per thread -> full 512-wide row per wave
    const float* wh = w + ((d0 >> 6) << 8);
    float acc[8] = {0.f, 0.f, 0.f, 0.f, 0.f, 0.f, 0.f, 0.f};
    for (int nn = rg; nn < 256; nn += 4) {
        const uint4 u = *(const uint4*)(xb + (((size_t)(b * 8192 + n0 + nn)) << 9) + d0);
        float ww = wh[nn];
        acc[0] += ww * __uint_as_float(u.x << 16);
        acc[1] += ww * __uint_as_float(u.x & 0xffff0000u);
        acc[2] += ww * __uint_as_float(u.y << 16);
        acc[3] += ww * __uint_as_float(u.y & 0xffff0000u);
        acc[4] += ww * __uint_as_float(u.z << 16);
        acc[5] += ww * __uint_as_float(u.z & 0xffff0000u);
        acc[6] += ww * __uint_as_float(u.w << 16);
        acc[7] += ww * __uint_as_float(u.w & 0xffff0000u);
    }
#pragma unroll
    for (int j = 0; j < 8; ++j) atomicAdd(&out[b * 512 + d0 + j], acc[j]);
}

// ---------------------------------------------------------------- launch
extern "C" void kernel_launch(void* const* d_in, const int* in_sizes, int n_in,
                              void* d_out, int out_size, void* d_ws, size_t ws_size,
                              hipStream_t stream) {
    const float* x  = (const float*)d_in[0];
    const float* Wk = (const float*)d_in[1];
    const float* Wg = (const float*)d_in[2];
    const float* q  = (const float*)d_in[3];
    float* out = (float*)d_out;

    char* ws = (char*)d_ws;
    unsigned short* xb  = (unsigned short*)ws;                        // 134217728 B
    unsigned short* wkb = (unsigned short*)(ws + 134217728ull);       // 524288 B
    unsigned short* wgb = (unsigned short*)(ws + 134742016ull);       // 524288 B
    float* s_buf = (float*)(ws + 135266304ull);                       // 4194304 B
    float* mb = (float*)(ws + 139460608ull);                          // 512 B
    float* lb = (float*)(ws + 139461120ull);                          // 512 B

    hipMemsetAsync(d_out, 0, 512 * B_ * sizeof(float), stream);

    hipLaunchKernelGGL(cvt_kernel, dim3(8192), dim3(256), 0, stream, x, xb, (B_ * N_ * D_) / 4);
    hipLaunchKernelGGL(cvt_kernel, dim3(256), dim3(256), 0, stream, Wk, wkb, (D_ * D_) / 4);
    hipLaunchKernelGGL(cvt_kernel, dim3(256), dim3(256), 0, stream, Wg, wgb, (D_ * D_) / 4);
    hipLaunchKernelGGL(gemm_score_kernel, dim3(4, 1024), dim3(256), 0, stream, xb, wkb, wgb, q, s_buf);
    hipLaunchKernelGGL(stats_kernel, dim3(128), dim3(256), 0, stream, s_buf, mb, lb);
    hipLaunchKernelGGL(out_kernel, dim3(512), dim3(256), 0, stream, xb, s_buf, mb, lb, out);
}

// Round 2
// 630.698 us; speedup vs baseline: 1.0306x; 1.0306x over previous
//
#include <hip/hip_runtime.h>
#include <hip/hip_bf16.h>

// Problem constants
#define H_ 8
#define D_ 512
#define DK_ 64
#define B_ 16
#define N_ 8192
#define M_ (B_ * N_)  // 131072 rows

typedef __attribute__((ext_vector_type(8))) short short8;
typedef __attribute__((ext_vector_type(4))) float floatx4;

// ---------------------------------------------------------------- helpers
__device__ __forceinline__ void glds16(const void* g, void* l) {
    // 16B-wide direct global->LDS DMA. LDS dest = wave-uniform base + lane*16.
    __builtin_amdgcn_global_load_lds((const __attribute__((address_space(1))) void*)g,
                                     (__attribute__((address_space(3))) void*)l,
                                     16, 0, 0);
}

__device__ __forceinline__ unsigned short f2bf(float f) {  // RNE
    unsigned u = __float_as_uint(f);
    return (unsigned short)((u + 0x7fffu + ((u >> 16) & 1u)) >> 16);
}

// pack two fp32 -> two bf16 (round-half-up): low16 = bf(x), high16 = bf(y)
__device__ __forceinline__ unsigned pack_bf2(float x, float y) {
    return __builtin_amdgcn_perm(__float_as_uint(y) + 0x8000u,
                                 __float_as_uint(x) + 0x8000u, 0x07060302u);
}

// ---------------------------------------------------------------- kernel 0: fp32 -> bf16 (weights only, 1 MB total)
__global__ __launch_bounds__(256) void cvt_kernel(const float* __restrict__ src,
                                                  unsigned short* __restrict__ dst, int n4) {
    int i = blockIdx.x * blockDim.x + threadIdx.x;
    int stride = gridDim.x * blockDim.x;
    for (; i < n4; i += stride) {
        float4 v = ((const float4*)src)[i];
        ushort4 o;
        o.x = f2bf(v.x); o.y = f2bf(v.y); o.z = f2bf(v.z); o.w = f2bf(v.w);
        ((ushort4*)dst)[i] = o;
    }
}

// ---------------------------------------------------------------- kernel 1: fused double-GEMM + gate + query-dot
// A (=x) staged fp32 directly from HBM (no xb materialization), converted to bf16
// at fragment-load time. LDS XOR-swizzled for conflict-free phased b128 reads.
// Tile: BM=128 x BN=128 (2 heads), BK=32, 256 threads, wave -> 64x64 quadrant.
__global__ __launch_bounds__(256, 2) void gemm_score_kernel(
    const float* __restrict__ x,             // (M_, 512) fp32
    const unsigned short* __restrict__ wkb,  // (512, 512) bf16
    const unsigned short* __restrict__ wgb,  // (512, 512) bf16
    const float* __restrict__ query,         // (8, 64) fp32
    float* __restrict__ s_buf)               // (B_, H_, N_) fp32
{
    __shared__ float lds_a[128 * 32];           // 16 KB fp32, chunk-swizzled
    __shared__ unsigned short lds_k[128 * 32];  // 8 KB bf16, chunk-swizzled
    __shared__ unsigned short lds_g[128 * 32];  // 8 KB

    const int t = threadIdx.x;
    const int lane = t & 63;
    const int wave = t >> 6;
    const int wm = wave >> 1, wn = wave & 1;
    const int jc = blockIdx.x * 128;   // output-column tile (4 tiles = 8 heads)
    const int m0 = blockIdx.y * 128;   // row tile (1024 tiles)

    floatx4 acc_k[4][4], acc_g[4][4];
#pragma unroll
    for (int i = 0; i < 4; ++i)
#pragma unroll
        for (int j = 0; j < 4; ++j) { acc_k[i][j] = (floatx4)0.f; acc_g[i][j] = (floatx4)0.f; }

    // A staging: 128 rows x 8 chunks(16B=4 floats) = 1024 chunks; 4 glds16/thread.
    // LDS slot p holds global chunk (r = p>>3, c = (p&7) ^ (r&7)).
    int ar[4], ac[4];
#pragma unroll
    for (int i = 0; i < 4; ++i) {
        int p = i * 256 + t;
        int r = p >> 3;
        ar[i] = r;
        ac[i] = (p & 7) ^ (r & 7);
    }
    // B staging: 128 rows x 4 chunks(16B=8 bf16) = 512 chunks; 2 glds16/thread/tile.
    // LDS slot p holds global chunk (r = p>>2, c = (p&3) ^ ((r>>1)&3)).
    int br[2], bc[2];
#pragma unroll
    for (int i = 0; i < 2; ++i) {
        int p = i * 256 + t;
        int r = p >> 2;
        br[i] = r;
        bc[i] = (p & 3) ^ ((r >> 1) & 3);
    }

    const int fr = lane & 15;   // fragment row (A) / col (B)
    const int q  = lane >> 4;   // k-quarter: k elements [8q, 8q+8)
    const int sw_a0 = (2 * q) ^ (fr & 7);        // LDS slot of A chunk 2q
    const int sw_a1 = sw_a0 ^ 1;                 // LDS slot of A chunk 2q+1
    const int sw_b  = q ^ ((fr >> 1) & 3);       // LDS slot of B chunk q

    for (int k0 = 0; k0 < 512; k0 += 32) {
#pragma unroll
        for (int i = 0; i < 4; ++i)
            glds16(x + (size_t)(m0 + ar[i]) * 512 + k0 + ac[i] * 4,
                   lds_a + (size_t)(i * 256 + t) * 4);
#pragma unroll
        for (int i = 0; i < 2; ++i) {
            glds16(wkb + (size_t)(jc + br[i]) * 512 + k0 + bc[i] * 8,
                   lds_k + (size_t)(i * 256 + t) * 8);
            glds16(wgb + (size_t)(jc + br[i]) * 512 + k0 + bc[i] * 8,
                   lds_g + (size_t)(i * 256 + t) * 8);
        }
        __syncthreads();

        short8 a[4], bk[4], bg[4];
#pragma unroll
        for (int mi = 0; mi < 4; ++mi) {
            int r = wm * 64 + mi * 16 + fr;
            float4 f0 = *(const float4*)(lds_a + (r * 8 + sw_a0) * 4);  // k [8q,8q+4)
            float4 f1 = *(const float4*)(lds_a + (r * 8 + sw_a1) * 4);  // k [8q+4,8q+8)
            union { unsigned u[4]; short8 s; } tmp;
            tmp.u[0] = pack_bf2(f0.x, f0.y);
            tmp.u[1] = pack_bf2(f0.z, f0.w);
            tmp.u[2] = pack_bf2(f1.x, f1.y);
            tmp.u[3] = pack_bf2(f1.z, f1.w);
            a[mi] = tmp.s;
        }
#pragma unroll
        for (int ni = 0; ni < 4; ++ni) {
            int r = wn * 64 + ni * 16 + fr;
            bk[ni] = *(const short8*)(lds_k + (r * 4 + sw_b) * 8);
            bg[ni] = *(const short8*)(lds_g + (r * 4 + sw_b) * 8);
        }
#pragma unroll
        for (int mi = 0; mi < 4; ++mi)
#pragma unroll
            for (int ni = 0; ni < 4; ++ni) {
                acc_k[mi][ni] = __builtin_amdgcn_mfma_f32_16x16x32_bf16(a[mi], bk[ni], acc_k[mi][ni], 0, 0, 0);
                acc_g[mi][ni] = __builtin_amdgcn_mfma_f32_16x16x32_bf16(a[mi], bg[ni], acc_g[mi][ni], 0, 0, 0);
            }
        __syncthreads();
    }

    // Epilogue: gated = tanh(K)*sigmoid(G); score = q . gated, reduce over 16 lanes.
    // C/D layout: col = lane&15, row = (lane>>4)*4 + reg.
    const int h = blockIdx.x * 2 + wn;  // this wave's head
    float qv[4];
#pragma unroll
    for (int ni = 0; ni < 4; ++ni) qv[ni] = query[h * 64 + ni * 16 + fr];

#pragma unroll
    for (int mi = 0; mi < 4; ++mi) {
#pragma unroll
        for (int r = 0; r < 4; ++r) {
            float v = 0.f;
#pragma unroll
            for (int ni = 0; ni < 4; ++ni) {
                float kv = acc_k[mi][ni][r];
                float gv = acc_g[mi][ni][r];
                float e2k = __expf(2.f * kv);
                float th = 1.f - 2.f / (e2k + 1.f);       // tanh, overflow-safe
                float sg = 1.f / (1.f + __expf(-gv));     // sigmoid
                v += qv[ni] * th * sg;
            }
            v += __shfl_xor(v, 1);
            v += __shfl_xor(v, 2);
            v += __shfl_xor(v, 4);
            v += __shfl_xor(v, 8);
            if (fr == 0) {
                int mg = m0 + wm * 64 + mi * 16 + (lane >> 4) * 4 + r;
                int b = mg >> 13, n = mg & 8191;
                s_buf[((size_t)(b * 8 + h) << 13) + n] = v;
            }
        }
    }
}

// ---------------------------------------------------------------- kernel 2: per-(b,h) softmax stats
__global__ __launch_bounds__(256) void stats_kernel(const float* __restrict__ s_buf,
                                                    float* __restrict__ mb, float* __restrict__ lb) {
    const int bh = blockIdx.x;  // 0..127
    const float* s = s_buf + ((size_t)bh << 13);
    const int t = threadIdx.x;
    float mx = -3.0e38f;
    for (int i = t; i < 8192; i += 256) mx = fmaxf(mx, s[i]);
#pragma unroll
    for (int m = 32; m > 0; m >>= 1) mx = fmaxf(mx, __shfl_xor(mx, m));
    __shared__ float red[8];
    if ((t & 63) == 0) red[t >> 6] = mx;
    __syncthreads();
    mx = fmaxf(fmaxf(red[0], red[1]), fmaxf(red[2], red[3]));
    float sum = 0.f;
    for (int i = t; i < 8192; i += 256) sum += __expf(s[i] - mx);
#pragma unroll
    for (int m = 32; m > 0; m >>= 1) sum += __shfl_xor(sum, m);
    if ((t & 63) == 0) red[4 + (t >> 6)] = sum;
    __syncthreads();
    if (t == 0) { mb[bh] = mx; lb[bh] = red[4] + red[5] + red[6] + red[7]; }
}

// ---------------------------------------------------------------- kernel 3: out[b,d] = sum_n w[b,h(d),n] * x[b,n,d]
__global__ __launch_bounds__(256) void out_kernel(
    const float* __restrict__ x, const float* __restrict__ s_buf,
    const float* __restrict__ mb, const float* __restrict__ lb,
    float* __restrict__ out) {
    const int b = blockIdx.x >> 5;      // 16
    const int chunk = blockIdx.x & 31;  // 32 chunks of 256 rows
    const int n0 = chunk * 256;
    const int t = threadIdx.x;
    __shared__ float w[8 * 256];
    for (int i = t; i < 2048; i += 256) {
        int hh = i >> 8, nn = i & 255;
        int bh = b * 8 + hh;
        w[i] = __expf(s_buf[((size_t)bh << 13) + n0 + nn] - mb[bh]) / lb[bh];
    }
    __syncthreads();
    const int rg = t >> 6;            // 4 row-groups
    const int d0 = (t & 63) * 8;      // 8 fp32 per thread -> full 512-wide row per wave
    const float* wh = w + ((d0 >> 6) << 8);
    float acc[8] = {0.f, 0.f, 0.f, 0.f, 0.f, 0.f, 0.f, 0.f};
    for (int nn = rg; nn < 256; nn += 4) {
        const float4* row = (const float4*)(x + (((size_t)(b * 8192 + n0 + nn)) << 9) + d0);
        float4 v0 = row[0];
        float4 v1 = row[1];
        float ww = wh[nn];
        acc[0] += ww * v0.x; acc[1] += ww * v0.y;
        acc[2] += ww * v0.z; acc[3] += ww * v0.w;
        acc[4] += ww * v1.x; acc[5] += ww * v1.y;
        acc[6] += ww * v1.z; acc[7] += ww * v1.w;
    }
#pragma unroll
    for (int j = 0; j < 8; ++j) atomicAdd(&out[b * 512 + d0 + j], acc[j]);
}

// ---------------------------------------------------------------- launch
extern "C" void kernel_launch(void* const* d_in, const int* in_sizes, int n_in,
                              void* d_out, int out_size, void* d_ws, size_t ws_size,
                              hipStream_t stream) {
    const float* x  = (const float*)d_in[0];
    const float* Wk = (const float*)d_in[1];
    const float* Wg = (const float*)d_in[2];
    const float* q  = (const float*)d_in[3];
    float* out = (float*)d_out;

    // ws layout (total ~5.25 MB — small ws keeps the harness's per-iter
    // 0xAA re-poison traffic negligible)
    char* ws = (char*)d_ws;
    unsigned short* wkb = (unsigned short*)ws;                   // 524288 B
    unsigned short* wgb = (unsigned short*)(ws + 524288ull);     // 524288 B
    float* s_buf = (float*)(ws + 1048576ull);                    // 4194304 B
    float* mb = (float*)(ws + 5242880ull);                       // 512 B
    float* lb = (float*)(ws + 5243392ull);                       // 512 B

    hipMemsetAsync(d_out, 0, 512 * B_ * sizeof(float), stream);

    hipLaunchKernelGGL(cvt_kernel, dim3(256), dim3(256), 0, stream, Wk, wkb, (D_ * D_) / 4);
    hipLaunchKernelGGL(cvt_kernel, dim3(256), dim3(256), 0, stream, Wg, wgb, (D_ * D_) / 4);
    hipLaunchKernelGGL(gemm_score_kernel, dim3(4, 1024), dim3(256), 0, stream, x, wkb, wgb, q, s_buf);
    hipLaunchKernelGGL(stats_kernel, dim3(128), dim3(256), 0, stream, s_buf, mb, lb);
    hipLaunchKernelGGL(out_kernel, dim3(512), dim3(256), 0, stream, x, s_buf, mb, lb, out);
}

// Round 3
// 584.732 us; speedup vs baseline: 1.1117x; 1.0786x over previous
//
#include <hip/hip_runtime.h>
#include <hip/hip_bf16.h>

// Problem constants
#define H_ 8
#define D_ 512
#define DK_ 64
#define B_ 16
#define N_ 8192
#define M_ (B_ * N_)  // 131072 rows

typedef __attribute__((ext_vector_type(8))) short short8;
typedef __attribute__((ext_vector_type(4))) float floatx4;

// ---------------------------------------------------------------- helpers
__device__ __forceinline__ void glds16(const void* g, void* l) {
    // 16B-wide direct global->LDS DMA. LDS dest = wave-uniform base + lane*16.
    __builtin_amdgcn_global_load_lds((const __attribute__((address_space(1))) void*)g,
                                     (__attribute__((address_space(3))) void*)l,
                                     16, 0, 0);
}

__device__ __forceinline__ unsigned short f2bf(float f) {  // RNE
    unsigned u = __float_as_uint(f);
    return (unsigned short)((u + 0x7fffu + ((u >> 16) & 1u)) >> 16);
}

// pack two fp32 -> two bf16 (round-half-up): low16 = bf(x), high16 = bf(y)
__device__ __forceinline__ unsigned pack_bf2(float x, float y) {
    return __builtin_amdgcn_perm(__float_as_uint(y) + 0x8000u,
                                 __float_as_uint(x) + 0x8000u, 0x07060302u);
}

__device__ __forceinline__ short8 pack_bf8(float4 lo, float4 hi) {
    union { unsigned u[4]; short8 s; } tmp;
    tmp.u[0] = pack_bf2(lo.x, lo.y);
    tmp.u[1] = pack_bf2(lo.z, lo.w);
    tmp.u[2] = pack_bf2(hi.x, hi.y);
    tmp.u[3] = pack_bf2(hi.z, hi.w);
    return tmp.s;
}

// ---------------------------------------------------------------- kernel 0: fp32 -> bf16 (weights only, 1 MB total)
__global__ __launch_bounds__(256) void cvt_kernel(const float* __restrict__ src,
                                                  unsigned short* __restrict__ dst, int n4) {
    int i = blockIdx.x * blockDim.x + threadIdx.x;
    int stride = gridDim.x * blockDim.x;
    for (; i < n4; i += stride) {
        float4 v = ((const float4*)src)[i];
        ushort4 o;
        o.x = f2bf(v.x); o.y = f2bf(v.y); o.z = f2bf(v.z); o.w = f2bf(v.w);
        ((ushort4*)dst)[i] = o;
    }
}

// ---------------------------------------------------------------- kernel 1: fused double-GEMM + gate + query-dot
// BM=128, BN=128 (2 heads), BK=64, 256 threads, wave -> 64x64 quadrant.
// A: fp32 from HBM -> regs -> bf16 pack -> swizzled LDS (ds_write_b128).
// B (Wk,Wg): bf16 via glds16 with source-side swizzle.
// Swizzle: chunk c (16B) of row r stored at slot c ^ ((r&1)<<2) ^ ((r>>1)&3).
// Grid: 1-D 4096, remapped so the 4 jc-siblings of an m-tile share an XCD.
__global__ __launch_bounds__(256, 2) void gemm_score_kernel(
    const float* __restrict__ x,             // (M_, 512) fp32
    const unsigned short* __restrict__ wkb,  // (512, 512) bf16
    const unsigned short* __restrict__ wgb,  // (512, 512) bf16
    const float* __restrict__ query,         // (8, 64) fp32
    float* __restrict__ s_buf)               // (B_, H_, N_) fp32
{
    __shared__ unsigned short lds_a[128 * 64];  // 16 KB bf16
    __shared__ unsigned short lds_k[128 * 64];  // 16 KB
    __shared__ unsigned short lds_g[128 * 64];  // 16 KB

    const int t = threadIdx.x;
    const int lane = t & 63;
    const int wave = t >> 6;
    const int wm = wave >> 1, wn = wave & 1;

    // XCD-aware remap: siblings (same m-tile, 4 jc) -> ids 8 apart -> same XCD.
    const int g = blockIdx.x;          // 0..4095
    const int xcd = g & 7;
    const int s = g >> 3;              // 0..511
    const int jt = s & 3;              // jc tile 0..3
    const int mt = ((s >> 2) << 3) | xcd;  // 0..1023
    const int jc = jt * 128;
    const int m0 = mt * 128;

    floatx4 acc_k[4][4], acc_g[4][4];
#pragma unroll
    for (int i = 0; i < 4; ++i)
#pragma unroll
        for (int j = 0; j < 4; ++j) { acc_k[i][j] = (floatx4)0.f; acc_g[i][j] = (floatx4)0.f; }

    // ---- A staging setup: thread t handles rows {r0, r0+64}, chunks {c0, c0+4}
    const int r0 = t >> 2;        // 0..63
    const int c0 = t & 3;         // 0..3
    const int swr = ((r0 & 1) << 2) ^ ((r0 >> 1) & 3);  // same for r0+64
    const float* pA0 = x + (size_t)(m0 + r0) * 512 + c0 * 8;
    const float* pA1 = pA0 + 64 * 512;
    unsigned short* wA00 = lds_a + ((r0 * 8) + (c0 ^ swr)) * 8;
    unsigned short* wA01 = lds_a + ((r0 * 8) + ((c0 ^ swr) ^ 4)) * 8;
    unsigned short* wA10 = wA00 + 64 * 64;  // row r0+64
    unsigned short* wA11 = wA01 + 64 * 64;

    // ---- B staging setup: 4 glds16 per tile per thread; slot p holds chunk
    // (r = p>>3, c = (p&7) ^ swz(r))
    int boff[4];
#pragma unroll
    for (int i = 0; i < 4; ++i) {
        int p = i * 256 + t;
        int r = p >> 3;
        int c = (p & 7) ^ (((r & 1) << 2) ^ ((r >> 1) & 3));
        boff[i] = (jc + r) * 512 + c * 8;   // bf16 elements
    }

    // ---- fragment-read setup
    const int fr = lane & 15;
    const int q  = lane >> 4;
    const int swf = ((fr & 1) << 2) ^ ((fr >> 1) & 3);

    for (int k0 = 0; k0 < 512; k0 += 64) {
        // B tiles: async DMA (no VGPR round-trip)
#pragma unroll
        for (int i = 0; i < 4; ++i) {
            glds16(wkb + boff[i] + k0, lds_k + (size_t)(i * 256 + t) * 8);
            glds16(wgb + boff[i] + k0, lds_g + (size_t)(i * 256 + t) * 8);
        }
        // A tile: fp32 loads -> bf16 pack -> swizzled LDS writes
        float4 a00 = *(const float4*)(pA0 + k0);
        float4 a01 = *(const float4*)(pA0 + k0 + 4);
        float4 a02 = *(const float4*)(pA0 + k0 + 32);
        float4 a03 = *(const float4*)(pA0 + k0 + 36);
        float4 a10 = *(const float4*)(pA1 + k0);
        float4 a11 = *(const float4*)(pA1 + k0 + 4);
        float4 a12 = *(const float4*)(pA1 + k0 + 32);
        float4 a13 = *(const float4*)(pA1 + k0 + 36);
        *(short8*)wA00 = pack_bf8(a00, a01);
        *(short8*)wA01 = pack_bf8(a02, a03);
        *(short8*)wA10 = pack_bf8(a10, a11);
        *(short8*)wA11 = pack_bf8(a12, a13);
        __syncthreads();

#pragma unroll
        for (int kc = 0; kc < 2; ++kc) {
            const int sl = ((kc * 4 + q) ^ swf) * 8;
            short8 a[4], bk[4], bg[4];
#pragma unroll
            for (int mi = 0; mi < 4; ++mi)
                a[mi] = *(const short8*)(lds_a + (wm * 64 + mi * 16 + fr) * 64 + sl);
#pragma unroll
            for (int ni = 0; ni < 4; ++ni) {
                bk[ni] = *(const short8*)(lds_k + (wn * 64 + ni * 16 + fr) * 64 + sl);
                bg[ni] = *(const short8*)(lds_g + (wn * 64 + ni * 16 + fr) * 64 + sl);
            }
#pragma unroll
            for (int mi = 0; mi < 4; ++mi)
#pragma unroll
                for (int ni = 0; ni < 4; ++ni) {
                    acc_k[mi][ni] = __builtin_amdgcn_mfma_f32_16x16x32_bf16(a[mi], bk[ni], acc_k[mi][ni], 0, 0, 0);
                    acc_g[mi][ni] = __builtin_amdgcn_mfma_f32_16x16x32_bf16(a[mi], bg[ni], acc_g[mi][ni], 0, 0, 0);
                }
        }
        __syncthreads();
    }

    // Epilogue: gated = tanh(K)*sigmoid(G); score = q . gated, reduce over 16 lanes.
    // C/D layout: col = lane&15, row = (lane>>4)*4 + reg.
    const int h = jt * 2 + wn;  // this wave's head
    float qv[4];
#pragma unroll
    for (int ni = 0; ni < 4; ++ni) qv[ni] = query[h * 64 + ni * 16 + fr];

#pragma unroll
    for (int mi = 0; mi < 4; ++mi) {
#pragma unroll
        for (int r = 0; r < 4; ++r) {
            float v = 0.f;
#pragma unroll
            for (int ni = 0; ni < 4; ++ni) {
                float kv = acc_k[mi][ni][r];
                float gv = acc_g[mi][ni][r];
                float e2k = __expf(2.f * kv);
                float th = 1.f - 2.f / (e2k + 1.f);       // tanh, overflow-safe
                float sg = 1.f / (1.f + __expf(-gv));     // sigmoid
                v += qv[ni] * th * sg;
            }
            v += __shfl_xor(v, 1);
            v += __shfl_xor(v, 2);
            v += __shfl_xor(v, 4);
            v += __shfl_xor(v, 8);
            if (fr == 0) {
                int mg = m0 + wm * 64 + mi * 16 + (lane >> 4) * 4 + r;
                int b = mg >> 13, n = mg & 8191;
                s_buf[((size_t)(b * 8 + h) << 13) + n] = v;
            }
        }
    }
}

// ---------------------------------------------------------------- kernel 2: per-(b,h) softmax stats
__global__ __launch_bounds__(256) void stats_kernel(const float* __restrict__ s_buf,
                                                    float* __restrict__ mb, float* __restrict__ lb) {
    const int bh = blockIdx.x;  // 0..127
    const float* s = s_buf + ((size_t)bh << 13);
    const int t = threadIdx.x;
    float mx = -3.0e38f;
    for (int i = t; i < 8192; i += 256) mx = fmaxf(mx, s[i]);
#pragma unroll
    for (int m = 32; m > 0; m >>= 1) mx = fmaxf(mx, __shfl_xor(mx, m));
    __shared__ float red[8];
    if ((t & 63) == 0) red[t >> 6] = mx;
    __syncthreads();
    mx = fmaxf(fmaxf(red[0], red[1]), fmaxf(red[2], red[3]));
    float sum = 0.f;
    for (int i = t; i < 8192; i += 256) sum += __expf(s[i] - mx);
#pragma unroll
    for (int m = 32; m > 0; m >>= 1) sum += __shfl_xor(sum, m);
    if ((t & 63) == 0) red[4 + (t >> 6)] = sum;
    __syncthreads();
    if (t == 0) { mb[bh] = mx; lb[bh] = red[4] + red[5] + red[6] + red[7]; }
}

// ---------------------------------------------------------------- kernel 3: out[b,d] = sum_n w[b,h(d),n] * x[b,n,d]
__global__ __launch_bounds__(256) void out_kernel(
    const float* __restrict__ x, const float* __restrict__ s_buf,
    const float* __restrict__ mb, const float* __restrict__ lb,
    float* __restrict__ out) {
    const int b = blockIdx.x >> 5;      // 16
    const int chunk = blockIdx.x & 31;  // 32 chunks of 256 rows
    const int n0 = chunk * 256;
    const int t = threadIdx.x;
    __shared__ float w[8 * 256];
    for (int i = t; i < 2048; i += 256) {
        int hh = i >> 8, nn = i & 255;
        int bh = b * 8 + hh;
        w[i] = __expf(s_buf[((size_t)bh << 13) + n0 + nn] - mb[bh]) / lb[bh];
    }
    __syncthreads();
    const int rg = t >> 6;            // 4 row-groups
    const int d0 = (t & 63) * 8;      // 8 fp32 per thread -> full 512-wide row per wave
    const float* wh = w + ((d0 >> 6) << 8);
    float acc[8] = {0.f, 0.f, 0.f, 0.f, 0.f, 0.f, 0.f, 0.f};
    for (int nn = rg; nn < 256; nn += 4) {
        const float4* row = (const float4*)(x + (((size_t)(b * 8192 + n0 + nn)) << 9) + d0);
        float4 v0 = row[0];
        float4 v1 = row[1];
        float ww = wh[nn];
        acc[0] += ww * v0.x; acc[1] += ww * v0.y;
        acc[2] += ww * v0.z; acc[3] += ww * v0.w;
        acc[4] += ww * v1.x; acc[5] += ww * v1.y;
        acc[6] += ww * v1.z; acc[7] += ww * v1.w;
    }
#pragma unroll
    for (int j = 0; j < 8; ++j) atomicAdd(&out[b * 512 + d0 + j], acc[j]);
}

// ---------------------------------------------------------------- launch
extern "C" void kernel_launch(void* const* d_in, const int* in_sizes, int n_in,
                              void* d_out, int out_size, void* d_ws, size_t ws_size,
                              hipStream_t stream) {
    const float* x  = (const float*)d_in[0];
    const float* Wk = (const float*)d_in[1];
    const float* Wg = (const float*)d_in[2];
    const float* q  = (const float*)d_in[3];
    float* out = (float*)d_out;

    // ws layout (total ~5.25 MB)
    char* ws = (char*)d_ws;
    unsigned short* wkb = (unsigned short*)ws;                   // 524288 B
    unsigned short* wgb = (unsigned short*)(ws + 524288ull);     // 524288 B
    float* s_buf = (float*)(ws + 1048576ull);                    // 4194304 B
    float* mb = (float*)(ws + 5242880ull);                       // 512 B
    float* lb = (float*)(ws + 5243392ull);                       // 512 B

    hipMemsetAsync(d_out, 0, 512 * B_ * sizeof(float), stream);

    hipLaunchKernelGGL(cvt_kernel, dim3(256), dim3(256), 0, stream, Wk, wkb, (D_ * D_) / 4);
    hipLaunchKernelGGL(cvt_kernel, dim3(256), dim3(256), 0, stream, Wg, wgb, (D_ * D_) / 4);
    hipLaunchKernelGGL(gemm_score_kernel, dim3(4096), dim3(256), 0, stream, x, wkb, wgb, q, s_buf);
    hipLaunchKernelGGL(stats_kernel, dim3(128), dim3(256), 0, stream, s_buf, mb, lb);
    hipLaunchKernelGGL(out_kernel, dim3(512), dim3(256), 0, stream, x, s_buf, mb, lb, out);
}